// Round 9
// baseline (238.873 us; speedup 1.0000x reference)
//
#include <hip/hip_runtime.h>
#include <hip/hip_bf16.h>
#include <math.h>

typedef short s16x8 __attribute__((ext_vector_type(8)));
typedef float f32x4 __attribute__((ext_vector_type(4)));
typedef _Float16 f16x4 __attribute__((ext_vector_type(4)));
typedef __fp16 fp16x2 __attribute__((ext_vector_type(2)));
typedef unsigned short u16;

#define NHEADS 12
#define SEQ 2048
#define NBH 24          // B*H
#define KDIM 768
#define LOG2E 1.44269504088896f

// XOR swizzle for u16 tiles with 64-u16 (128 B) rows, 8-u16 (16 B) granularity.
#define SWZ(row, col) (((row) * 64) + ((col) ^ (((row) & 7) << 3)))
// XOR swizzle for u16 tiles with 32-u16 (64 B) rows: chunk ^= row&3.
#define SWZ32(row, col) (((row) * 32) + ((col) ^ (((row) & 3) << 3)))

// global -> LDS direct, 16B per lane. LDS dest = wave-uniform base + lane*16.
#define GLOAD_LDS16(g, l) __builtin_amdgcn_global_load_lds( \
    (const __attribute__((address_space(1))) unsigned int*)(g), \
    (__attribute__((address_space(3))) unsigned int*)(l), 16, 0, 0)

static __device__ __forceinline__ u16 f2bf(float f) {
    union { float f; unsigned u; } v; v.f = f;
    unsigned r = v.u + 0x7fffu + ((v.u >> 16) & 1u);
    return (u16)(r >> 16);
}
static __device__ __forceinline__ u16 f2h(float f) {
    union { _Float16 h; u16 u; } v; v.h = (_Float16)f;
    return v.u;
}
static __device__ __forceinline__ f16x4 pack4(float a, float b, float c, float d) {
    union { fp16x2 h2[2]; f16x4 h4; } u;
    u.h2[0] = __builtin_amdgcn_cvt_pkrtz(a, b);
    u.h2[1] = __builtin_amdgcn_cvt_pkrtz(c, d);
    return u.h4;
}

// ---------------- f32 -> bf16 convert (z selects tensor; z=2 scales Wq; z=5 mask*log2e f32) ----
__global__ void cvt6_kernel(const float* __restrict__ s0, const float* __restrict__ s1,
                            const float* __restrict__ s2, const float* __restrict__ s3,
                            const float* __restrict__ s4, const float* __restrict__ s5,
                            u16* __restrict__ d0, u16* __restrict__ d1, u16* __restrict__ d2,
                            u16* __restrict__ d3, u16* __restrict__ d4, float* __restrict__ d5,
                            int n4a, int n4w, float qscl) {
    const int z = blockIdx.z;
    int i = blockIdx.x * blockDim.x + threadIdx.x;
    if (z == 5) {
        if (i < (2 * SEQ) / 4) {
            float4 f = ((const float4*)s5)[i];
            f.x *= LOG2E; f.y *= LOG2E; f.z *= LOG2E; f.w *= LOG2E;
            ((float4*)d5)[i] = f;
        }
        return;
    }
    const float* src = (z == 0) ? s0 : (z == 1) ? s1 : (z == 2) ? s2 : (z == 3) ? s3 : s4;
    u16* dst         = (z == 0) ? d0 : (z == 1) ? d1 : (z == 2) ? d2 : (z == 3) ? d3 : d4;
    const int n4     = (z < 2) ? n4a : n4w;
    const float scl  = (z == 2) ? qscl : 1.0f;
    if (i < n4) {
        float4 f = ((const float4*)src)[i];
        ushort4 o;
        o.x = f2bf(f.x * scl); o.y = f2bf(f.y * scl); o.z = f2bf(f.z * scl); o.w = f2bf(f.w * scl);
        ((ushort4*)dst)[i] = o;
    }
}

// ---------------- QKV projection GEMM (BK=32, dbuf, 1 barrier/K-step, 4 blocks/CU) --------
// z<2 (Q,K): MFMA operands SWAPPED (A=W, B=X) so reg-index j spans d -> ushort4 stores
//            into [bh][s][d] bf16. Q pre-scaled by inv_s*log2e via Wq/bq.
// z=2 (V):   normal order; writes TRANSPOSED+pi-PERMUTED [bh][d][s'] f16,
//            s' = s with bits[5:4]<->[3:2] swapped.
__launch_bounds__(256, 4)
__global__ void qkv_gemm(const u16* __restrict__ X, const u16* __restrict__ C,
                         const u16* __restrict__ W0, const u16* __restrict__ W1, const u16* __restrict__ W2,
                         const float* __restrict__ b0, const float* __restrict__ b1, const float* __restrict__ b2,
                         u16* __restrict__ Qo, u16* __restrict__ Ko, u16* __restrict__ Vo, float qscl) {
    const int z = blockIdx.z;
    const u16* A    = (z == 0) ? X  : C;
    const u16* W    = (z == 0) ? W0 : (z == 1) ? W1 : W2;
    const float* bi = (z == 0) ? b0 : (z == 1) ? b1 : b2;
    u16* out        = (z == 0) ? Qo : (z == 1) ? Ko : Vo;
    const float bscl = (z == 0) ? qscl : 1.0f;

    __shared__ u16 As[2][128 * 32];
    __shared__ u16 Bs[2][128 * 32];

    const int tid  = threadIdx.x;
    const int lane = tid & 63;
    const int wid  = tid >> 6;
    const int wr = wid >> 1, wc = wid & 1;
    const int l15 = lane & 15, lh = lane >> 4;
    const int mBase = blockIdx.x * 128;
    const int nBase = blockIdx.y * 128;

    // staging: 2 gload rounds per matrix per K-step (128x32 u16 = 8KB).
    size_t aSrc[2], bSrc[2]; int ldsOffG[2];
    #pragma unroll
    for (int i = 0; i < 2; ++i) {
        int L = tid * 8 + i * 2048;
        int row = L >> 5;
        int col = (L & 31) ^ ((row & 3) << 3);   // inverse swizzle on global source
        aSrc[i] = (size_t)(mBase + row) * KDIM + col;
        bSrc[i] = (size_t)(nBase + row) * KDIM + col;
        ldsOffG[i] = wid * 512 + i * 2048;
    }

    f32x4 acc[4][4] = {};

    // prologue: stage K-step 0 into buffer 0
    #pragma unroll
    for (int i = 0; i < 2; ++i) {
        GLOAD_LDS16(&A[aSrc[i]], &As[0][ldsOffG[i]]);
        GLOAD_LDS16(&W[bSrc[i]], &Bs[0][ldsOffG[i]]);
    }

    const int NIT = KDIM / 32;   // 24
    for (int it = 0; it < NIT; ++it) {
        const int cur = it & 1;
        __syncthreads();  // drains gload_lds: buf[cur] ready
        if (it + 1 < NIT) {
            const int kb = (it + 1) * 32;
            #pragma unroll
            for (int i = 0; i < 2; ++i) {
                GLOAD_LDS16(&A[aSrc[i] + kb], &As[cur ^ 1][ldsOffG[i]]);
                GLOAD_LDS16(&W[bSrc[i] + kb], &Bs[cur ^ 1][ldsOffG[i]]);
            }
        }
        s16x8 xf[4], wf[4];
        #pragma unroll
        for (int m = 0; m < 4; ++m)
            xf[m] = *(const s16x8*)(&As[cur][SWZ32(wr * 64 + m * 16 + l15, lh * 8)]);
        #pragma unroll
        for (int n = 0; n < 4; ++n)
            wf[n] = *(const s16x8*)(&Bs[cur][SWZ32(wc * 64 + n * 16 + l15, lh * 8)]);
        if (z < 2) {  // wave-uniform branch: swapped operands (D: col=s-row, reg=d-col)
            #pragma unroll
            for (int m = 0; m < 4; ++m)
                #pragma unroll
                for (int n = 0; n < 4; ++n)
                    acc[m][n] = __builtin_amdgcn_mfma_f32_16x16x32_bf16(wf[n], xf[m], acc[m][n], 0, 0, 0);
        } else {
            #pragma unroll
            for (int m = 0; m < 4; ++m)
                #pragma unroll
                for (int n = 0; n < 4; ++n)
                    acc[m][n] = __builtin_amdgcn_mfma_f32_16x16x32_bf16(xf[m], wf[n], acc[m][n], 0, 0, 0);
        }
    }

    if (z < 2) {
        // D[col=l15 -> s within m-block][reg j -> d within n-block]: ushort4 per (m,n)
        #pragma unroll
        for (int m = 0; m < 4; ++m) {
            int sg = mBase + wr * 64 + m * 16 + l15;
            int b = sg >> 11, s = sg & 2047;
            #pragma unroll
            for (int n = 0; n < 4; ++n) {
                int d0 = nBase + wc * 64 + n * 16 + lh * 4;
                int h = d0 >> 6, d = d0 & 63;
                float4 bv = *(const float4*)(&bi[d0]);
                ushort4 o;
                o.x = f2bf(acc[m][n][0] + bv.x * bscl);
                o.y = f2bf(acc[m][n][1] + bv.y * bscl);
                o.z = f2bf(acc[m][n][2] + bv.z * bscl);
                o.w = f2bf(acc[m][n][3] + bv.w * bscl);
                *(ushort4*)(&out[(((size_t)(b * NHEADS + h) * SEQ + s) << 6) + d]) = o;
            }
        }
    } else {
        // V: [bh][d][s'] f16, s' = pi(s); 4 consecutive s -> ushort4.
        #pragma unroll
        for (int m = 0; m < 4; ++m) {
            #pragma unroll
            for (int n = 0; n < 4; ++n) {
                int colg = nBase + wc * 64 + n * 16 + l15;
                float bv = bi[colg];
                int h = colg >> 6, d = colg & 63;
                int rowg0 = mBase + wr * 64 + m * 16 + lh * 4;
                int b = rowg0 >> 11, s = rowg0 & 2047;
                int sp = (s & ~0x3C) | (((s >> 2) & 3) << 4) | (((s >> 4) & 3) << 2);
                ushort4 o;
                o.x = f2h(acc[m][n][0] + bv);
                o.y = f2h(acc[m][n][1] + bv);
                o.z = f2h(acc[m][n][2] + bv);
                o.w = f2h(acc[m][n][3] + bv);
                *(ushort4*)(&out[(((size_t)(b * NHEADS + h) * 64 + d) << 11) + sp]) = o;
            }
        }
    }
}

// ---------------- flash attention (swapped-QK^T, register softmax, exp2 domain) ----------------
// grid: (SEQ/128, NBH, SPLIT?2:1). 8 waves x 16 q-rows (q = lane&15). KV tile = 64, dbuf,
// one barrier per tile. Mask staged to LDS once, folded in as MFMA C-init.
// Ballot-first defer-max; lazy lrun; partial O stored f16.
template<bool SPLIT>
__launch_bounds__(512)
__global__ void attn_kernel(const u16* __restrict__ Qg, const u16* __restrict__ Kg,
                            const u16* __restrict__ Vg,
                            const float* __restrict__ maskL, float* __restrict__ out,
                            u16* __restrict__ OpartH, float* __restrict__ MLpart) {
    __shared__ u16 Ks[2][64 * 64];
    __shared__ u16 Vt[2][64 * 64];
    __shared__ float maskLds[2048];

    const int tid  = threadIdx.x;
    const int lane = tid & 63;
    const int wid  = tid >> 6;
    const int bh = blockIdx.y;
    const int b = bh / NHEADS;
    const int h = bh % NHEADS;
    const int q0 = blockIdx.x * 128 + wid * 16;
    const int l15 = lane & 15, lh = lane >> 4;
    const int z = SPLIT ? blockIdx.z : 0;
    const int NT = SPLIT ? (SEQ / 128) : (SEQ / 64);
    const int tile0 = z * NT;

    // mask slice -> LDS once (NT*64 floats)
    for (int i = tid * 4; i < NT * 64; i += 512 * 4)
        *(float4*)(&maskLds[i]) = *(const float4*)(&maskL[(size_t)b * SEQ + (tile0 << 6) + i]);

    // staging: 512 threads x 16B = full 64x64 u16 tile in one gload round.
    const int srow = tid >> 3;
    const int scol = ((tid & 7) * 8) ^ ((srow & 7) << 3);
    const size_t kSrc = (((size_t)bh * SEQ + srow) << 6) + scol + ((size_t)tile0 << 12);
    const size_t vSrc = (((size_t)bh * 64 + srow) << 11) + scol + (size_t)tile0 * 64;
    const int ldsBase = wid * 512;   // u16 units; lane*8 added by HW

    s16x8 qf[2];
    #pragma unroll
    for (int kk = 0; kk < 2; ++kk)
        qf[kk] = *(const s16x8*)(&Qg[(((size_t)bh * SEQ + q0 + l15) << 6) + kk * 32 + lh * 8]);

    f32x4 oacc[4] = {};           // O^T frags: oacc[nd][j] = O[q=l15][d=nd*16+lh*4+j]
    float mrun = -1e30f, lrun = 0.f;   // lrun is per-lane partial (lazy reduce)

    GLOAD_LDS16(&Kg[kSrc], &Ks[0][ldsBase]);
    GLOAD_LDS16(&Vg[vSrc], &Vt[0][ldsBase]);

    for (int t = 0; t < NT; ++t) {
        const int cur = t & 1;
        __syncthreads();
        if (t + 1 < NT) {
            GLOAD_LDS16(&Kg[kSrc + ((size_t)(t + 1) << 12)], &Ks[cur ^ 1][ldsBase]);
            GLOAD_LDS16(&Vg[vSrc + (size_t)(t + 1) * 64],    &Vt[cur ^ 1][ldsBase]);
        }

        // C-init = mask (broadcast LDS read), then S^T = mfma(K, Q) accumulates on top
        f32x4 sacc[4];
        #pragma unroll
        for (int n = 0; n < 4; ++n) {
            float4 mv = *(const float4*)(&maskLds[t * 64 + n * 16 + lh * 4]);
            sacc[n][0] = mv.x; sacc[n][1] = mv.y; sacc[n][2] = mv.z; sacc[n][3] = mv.w;
        }
        __builtin_amdgcn_s_setprio(1);
        #pragma unroll
        for (int kk = 0; kk < 2; ++kk) {
            #pragma unroll
            for (int n = 0; n < 4; ++n) {
                s16x8 kf = *(const s16x8*)(&Ks[cur][SWZ(n * 16 + l15, kk * 32 + lh * 8)]);
                sacc[n] = __builtin_amdgcn_mfma_f32_16x16x32_bf16(kf, qf[kk], sacc[n], 0, 0, 0);
            }
        }
        __builtin_amdgcn_s_setprio(0);

        // lane-local max; cross-lane reduce only when rescale might be needed
        float tmax = sacc[0][0];
        #pragma unroll
        for (int n = 0; n < 4; ++n)
            #pragma unroll
            for (int j = 0; j < 4; ++j)
                tmax = fmaxf(tmax, sacc[n][j]);

        if (!__all(tmax - mrun <= 11.0f)) {
            float rmax = fmaxf(tmax, __shfl_xor(tmax, 16));
            rmax = fmaxf(rmax, __shfl_xor(rmax, 32));
            float mnew = fmaxf(mrun, rmax);
            float alpha = __builtin_amdgcn_exp2f(mrun - mnew);
            lrun *= alpha;
            #pragma unroll
            for (int nd = 0; nd < 4; ++nd)
                #pragma unroll
                for (int j = 0; j < 4; ++j)
                    oacc[nd][j] *= alpha;
            mrun = mnew;
        }

        f16x4 pf[4];   // B-frag (16x16x16): k = lh*4 + e == S^T D-layout
        #pragma unroll
        for (int n = 0; n < 4; ++n) {
            float p0 = __builtin_amdgcn_exp2f(sacc[n][0] - mrun);
            float p1 = __builtin_amdgcn_exp2f(sacc[n][1] - mrun);
            float p2 = __builtin_amdgcn_exp2f(sacc[n][2] - mrun);
            float p3 = __builtin_amdgcn_exp2f(sacc[n][3] - mrun);
            lrun += (p0 + p1) + (p2 + p3);
            pf[n] = pack4(p0, p1, p2, p3);
        }

        // PV: one 16B read covers frags n=2kk,2kk+1 (pi-permuted V layout)
        __builtin_amdgcn_s_setprio(1);
        #pragma unroll
        for (int kk = 0; kk < 2; ++kk) {
            #pragma unroll
            for (int nd = 0; nd < 4; ++nd) {
                s16x8 v2 = *(const s16x8*)(&Vt[cur][SWZ(nd * 16 + l15, lh * 16 + kk * 8)]);
                union { s16x8 s8; f16x4 h4[2]; } u; u.s8 = v2;
                oacc[nd] = __builtin_amdgcn_mfma_f32_16x16x16f16(u.h4[0], pf[2 * kk],     oacc[nd], 0, 0, 0);
                oacc[nd] = __builtin_amdgcn_mfma_f32_16x16x16f16(u.h4[1], pf[2 * kk + 1], oacc[nd], 0, 0, 0);
            }
        }
        __builtin_amdgcn_s_setprio(0);
    }

    // lazy lrun: reduce across the 4 lh groups sharing each q
    lrun += __shfl_xor(lrun, 16);
    lrun += __shfl_xor(lrun, 32);

    const float inv = 1.0f / lrun;
    const int s = q0 + l15;
    if (!SPLIT) {
        #pragma unroll
        for (int nd = 0; nd < 4; ++nd) {
            float4 o;
            o.x = oacc[nd][0] * inv; o.y = oacc[nd][1] * inv;
            o.z = oacc[nd][2] * inv; o.w = oacc[nd][3] * inv;
            *(float4*)(&out[(size_t)(b * SEQ + s) * (NHEADS * 64) + h * 64 + nd * 16 + lh * 4]) = o;
        }
    } else {
        const size_t rbase = ((size_t)(z * NBH + bh) * SEQ + s);
        #pragma unroll
        for (int nd = 0; nd < 4; ++nd) {
            union { f16x4 h4; ushort4 u4; } o;
            o.h4 = pack4(oacc[nd][0] * inv, oacc[nd][1] * inv,
                         oacc[nd][2] * inv, oacc[nd][3] * inv);
            *(ushort4*)(&OpartH[rbase * 64 + nd * 16 + lh * 4]) = o.u4;
        }
        if (lh == 0)
            *(float2*)(&MLpart[rbase * 2]) = make_float2(mrun, lrun);
    }
}

// ---------------- split-KV combine (f16 partials) ----------------
__global__ void combine_kernel(const u16* __restrict__ OpartH, const float* __restrict__ MLpart,
                               float* __restrict__ out) {
    int gid = blockIdx.x * 256 + threadIdx.x;   // NBH*SEQ*16 = 786432 threads
    int row = gid >> 4, d4 = gid & 15;
    float2 ml0 = ((const float2*)MLpart)[row];
    float2 ml1 = ((const float2*)MLpart)[NBH * SEQ + row];
    float m = fmaxf(ml0.x, ml1.x);
    float w0 = __builtin_amdgcn_exp2f(ml0.x - m) * ml0.y;
    float w1 = __builtin_amdgcn_exp2f(ml1.x - m) * ml1.y;
    float inv = 1.0f / (w0 + w1);
    w0 *= inv; w1 *= inv;
    union { ushort4 u4; f16x4 h4; } a, c;
    a.u4 = *(const ushort4*)(&OpartH[(size_t)row * 64 + d4 * 4]);
    c.u4 = *(const ushort4*)(&OpartH[(size_t)NBH * SEQ * 64 + (size_t)row * 64 + d4 * 4]);
    float4 o;
    o.x = (float)a.h4[0] * w0 + (float)c.h4[0] * w1;
    o.y = (float)a.h4[1] * w0 + (float)c.h4[1] * w1;
    o.z = (float)a.h4[2] * w0 + (float)c.h4[2] * w1;
    o.w = (float)a.h4[3] * w0 + (float)c.h4[3] * w1;
    int bh = row >> 11, s = row & 2047;
    int b = bh / NHEADS, hh = bh % NHEADS;
    *(float4*)(&out[(size_t)(b * SEQ + s) * (NHEADS * 64) + hh * 64 + d4 * 4]) = o;
}

extern "C" void kernel_launch(void* const* d_in, const int* in_sizes, int n_in,
                              void* d_out, int out_size, void* d_ws, size_t ws_size,
                              hipStream_t stream) {
    const float* hidden  = (const float*)d_in[0];
    const float* context = (const float*)d_in[1];
    const float* mask    = (const float*)d_in[2];
    const float* Wq = (const float*)d_in[3];
    const float* bq = (const float*)d_in[4];
    const float* Wk = (const float*)d_in[5];
    const float* bk = (const float*)d_in[6];
    const float* Wv = (const float*)d_in[7];
    const float* bv = (const float*)d_in[8];
    float* out = (float*)d_out;

    char* ws = (char*)d_ws;
    const size_t XSZ = (size_t)4096 * 768 * 2;
    const size_t WSZ = (size_t)768 * 768 * 2;
    u16* X16  = (u16*)(ws);
    u16* C16  = (u16*)(ws + XSZ);
    u16* W16q = (u16*)(ws + 2 * XSZ);
    u16* W16k = (u16*)(ws + 2 * XSZ + WSZ);
    u16* W16v = (u16*)(ws + 2 * XSZ + 2 * WSZ);
    u16* Q16  = (u16*)(ws + 2 * XSZ + 3 * WSZ);
    u16* K16  = (u16*)(ws + 3 * XSZ + 3 * WSZ);
    u16* V16  = (u16*)(ws + 4 * XSZ + 3 * WSZ);    // f16, [bh][d][s'] pi-permuted
    const size_t MASKL_OFF = 5 * XSZ + 3 * WSZ;
    float* maskL = (float*)(ws + MASKL_OFF);
    const size_t OPART_OFF = MASKL_OFF + 2 * SEQ * sizeof(float) + 256;
    u16* OpartH = (u16*)(ws + OPART_OFF);                           // 12.6 MB f16
    const size_t ML_OFF = OPART_OFF + (size_t)2 * NBH * SEQ * 64 * 2;
    float* MLpart = (float*)(ws + ML_OFF);
    const size_t WS_NEED_SPLIT = ML_OFF + (size_t)2 * NBH * SEQ * 2 * 4;

    const float qscl = (float)((1.0 / sqrt(64.0 + 1e-5)) * 1.44269504088896);

    const int n4x = 4096 * 768 / 4;
    const int n4w = 768 * 768 / 4;
    cvt6_kernel<<<dim3((n4x + 255) / 256, 1, 6), 256, 0, stream>>>(
        hidden, context, Wq, Wk, Wv, mask,
        X16, C16, W16q, W16k, W16v, maskL, n4x, n4w, qscl);

    qkv_gemm<<<dim3(4096 / 128, 768 / 128, 3), 256, 0, stream>>>(
        X16, C16, W16q, W16k, W16v, bq, bk, bv, Q16, K16, V16, qscl);

    if (ws_size >= WS_NEED_SPLIT) {
        attn_kernel<true><<<dim3(SEQ / 128, NBH, 2), 512, 0, stream>>>(
            Q16, K16, V16, maskL, out, OpartH, MLpart);
        combine_kernel<<<(NBH * SEQ * 16) / 256, 256, 0, stream>>>(OpartH, MLpart, out);
    } else {
        attn_kernel<false><<<dim3(SEQ / 128, NBH, 1), 512, 0, stream>>>(
            Q16, K16, V16, maskL, out, OpartH, MLpart);
    }
}

// Round 10
// 101.420 us; speedup vs baseline: 2.3553x; 2.3553x over previous
//
#include <hip/hip_runtime.h>
#include <hip/hip_bf16.h>
#include <math.h>

typedef short s16x8 __attribute__((ext_vector_type(8)));
typedef float f32x4 __attribute__((ext_vector_type(4)));
typedef _Float16 f16x4 __attribute__((ext_vector_type(4)));
typedef __fp16 fp16x2 __attribute__((ext_vector_type(2)));
typedef unsigned short u16;

#define NHEADS 12
#define SEQ 2048
#define NBH 24          // B*H
#define KDIM 768
#define LOG2E 1.44269504088896f

// XOR swizzle for u16 tiles with 64-u16 (128 B) rows, 8-u16 (16 B) granularity.
#define SWZ(row, col) (((row) * 64) + ((col) ^ (((row) & 7) << 3)))
// XOR swizzle for u16 tiles with 32-u16 (64 B) rows: chunk ^= row&3.
#define SWZ32(row, col) (((row) * 32) + ((col) ^ (((row) & 3) << 3)))

// global -> LDS direct, 16B per lane. LDS dest = wave-uniform base + lane*16.
#define GLOAD_LDS16(g, l) __builtin_amdgcn_global_load_lds( \
    (const __attribute__((address_space(1))) unsigned int*)(g), \
    (__attribute__((address_space(3))) unsigned int*)(l), 16, 0, 0)

static __device__ __forceinline__ u16 f2bf(float f) {
    union { float f; unsigned u; } v; v.f = f;
    unsigned r = v.u + 0x7fffu + ((v.u >> 16) & 1u);
    return (u16)(r >> 16);
}
static __device__ __forceinline__ u16 f2h(float f) {
    union { _Float16 h; u16 u; } v; v.h = (_Float16)f;
    return v.u;
}
static __device__ __forceinline__ f16x4 pack4(float a, float b, float c, float d) {
    union { fp16x2 h2[2]; f16x4 h4; } u;
    u.h2[0] = __builtin_amdgcn_cvt_pkrtz(a, b);
    u.h2[1] = __builtin_amdgcn_cvt_pkrtz(c, d);
    return u.h4;
}

// ---------------- f32 -> bf16 convert (z selects tensor; z=2 scales Wq; z=5 mask*log2e f32) ----
__global__ void cvt6_kernel(const float* __restrict__ s0, const float* __restrict__ s1,
                            const float* __restrict__ s2, const float* __restrict__ s3,
                            const float* __restrict__ s4, const float* __restrict__ s5,
                            u16* __restrict__ d0, u16* __restrict__ d1, u16* __restrict__ d2,
                            u16* __restrict__ d3, u16* __restrict__ d4, float* __restrict__ d5,
                            int n4a, int n4w, float qscl) {
    const int z = blockIdx.z;
    int i = blockIdx.x * blockDim.x + threadIdx.x;
    if (z == 5) {
        if (i < (2 * SEQ) / 4) {
            float4 f = ((const float4*)s5)[i];
            f.x *= LOG2E; f.y *= LOG2E; f.z *= LOG2E; f.w *= LOG2E;
            ((float4*)d5)[i] = f;
        }
        return;
    }
    const float* src = (z == 0) ? s0 : (z == 1) ? s1 : (z == 2) ? s2 : (z == 3) ? s3 : s4;
    u16* dst         = (z == 0) ? d0 : (z == 1) ? d1 : (z == 2) ? d2 : (z == 3) ? d3 : d4;
    const int n4     = (z < 2) ? n4a : n4w;
    const float scl  = (z == 2) ? qscl : 1.0f;
    if (i < n4) {
        float4 f = ((const float4*)src)[i];
        ushort4 o;
        o.x = f2bf(f.x * scl); o.y = f2bf(f.y * scl); o.z = f2bf(f.z * scl); o.w = f2bf(f.w * scl);
        ((ushort4*)dst)[i] = o;
    }
}

// ---------------- QKV projection GEMM (BK=32, dbuf, 1 barrier/K-step) ----------------
// 32KB LDS/block; NO forced min-waves (round-9 lesson: the cap caused 425MB scratch spill).
// z<2 (Q,K): MFMA operands SWAPPED (A=W, B=X) so reg-index j spans d -> ushort4 stores
//            into [bh][s][d] bf16. Q pre-scaled by inv_s*log2e via Wq/bq.
// z=2 (V):   normal order; writes TRANSPOSED+pi-PERMUTED [bh][d][s'] f16,
//            s' = s with bits[5:4]<->[3:2] swapped.
__launch_bounds__(256)
__global__ void qkv_gemm(const u16* __restrict__ X, const u16* __restrict__ C,
                         const u16* __restrict__ W0, const u16* __restrict__ W1, const u16* __restrict__ W2,
                         const float* __restrict__ b0, const float* __restrict__ b1, const float* __restrict__ b2,
                         u16* __restrict__ Qo, u16* __restrict__ Ko, u16* __restrict__ Vo, float qscl) {
    const int z = blockIdx.z;
    const u16* A    = (z == 0) ? X  : C;
    const u16* W    = (z == 0) ? W0 : (z == 1) ? W1 : W2;
    const float* bi = (z == 0) ? b0 : (z == 1) ? b1 : b2;
    u16* out        = (z == 0) ? Qo : (z == 1) ? Ko : Vo;
    const float bscl = (z == 0) ? qscl : 1.0f;

    __shared__ u16 As[2][128 * 32];
    __shared__ u16 Bs[2][128 * 32];

    const int tid  = threadIdx.x;
    const int lane = tid & 63;
    const int wid  = tid >> 6;
    const int wr = wid >> 1, wc = wid & 1;
    const int l15 = lane & 15, lh = lane >> 4;
    const int mBase = blockIdx.x * 128;
    const int nBase = blockIdx.y * 128;

    // staging: 2 gload rounds per matrix per K-step (128x32 u16 = 8KB).
    size_t aSrc[2], bSrc[2]; int ldsOffG[2];
    #pragma unroll
    for (int i = 0; i < 2; ++i) {
        int L = tid * 8 + i * 2048;
        int row = L >> 5;
        int col = (L & 31) ^ ((row & 3) << 3);   // inverse swizzle on global source
        aSrc[i] = (size_t)(mBase + row) * KDIM + col;
        bSrc[i] = (size_t)(nBase + row) * KDIM + col;
        ldsOffG[i] = wid * 512 + i * 2048;
    }

    f32x4 acc[4][4] = {};

    // prologue: stage K-step 0 into buffer 0
    #pragma unroll
    for (int i = 0; i < 2; ++i) {
        GLOAD_LDS16(&A[aSrc[i]], &As[0][ldsOffG[i]]);
        GLOAD_LDS16(&W[bSrc[i]], &Bs[0][ldsOffG[i]]);
    }

    const int NIT = KDIM / 32;   // 24
    for (int it = 0; it < NIT; ++it) {
        const int cur = it & 1;
        __syncthreads();  // drains gload_lds: buf[cur] ready
        if (it + 1 < NIT) {
            const int kb = (it + 1) * 32;
            #pragma unroll
            for (int i = 0; i < 2; ++i) {
                GLOAD_LDS16(&A[aSrc[i] + kb], &As[cur ^ 1][ldsOffG[i]]);
                GLOAD_LDS16(&W[bSrc[i] + kb], &Bs[cur ^ 1][ldsOffG[i]]);
            }
        }
        s16x8 xf[4], wf[4];
        #pragma unroll
        for (int m = 0; m < 4; ++m)
            xf[m] = *(const s16x8*)(&As[cur][SWZ32(wr * 64 + m * 16 + l15, lh * 8)]);
        #pragma unroll
        for (int n = 0; n < 4; ++n)
            wf[n] = *(const s16x8*)(&Bs[cur][SWZ32(wc * 64 + n * 16 + l15, lh * 8)]);
        if (z < 2) {  // wave-uniform branch: swapped operands (D: col=s-row, reg=d-col)
            #pragma unroll
            for (int m = 0; m < 4; ++m)
                #pragma unroll
                for (int n = 0; n < 4; ++n)
                    acc[m][n] = __builtin_amdgcn_mfma_f32_16x16x32_bf16(wf[n], xf[m], acc[m][n], 0, 0, 0);
        } else {
            #pragma unroll
            for (int m = 0; m < 4; ++m)
                #pragma unroll
                for (int n = 0; n < 4; ++n)
                    acc[m][n] = __builtin_amdgcn_mfma_f32_16x16x32_bf16(xf[m], wf[n], acc[m][n], 0, 0, 0);
        }
    }

    if (z < 2) {
        // D[col=l15 -> s within m-block][reg j -> d within n-block]: ushort4 per (m,n)
        #pragma unroll
        for (int m = 0; m < 4; ++m) {
            int sg = mBase + wr * 64 + m * 16 + l15;
            int b = sg >> 11, s = sg & 2047;
            #pragma unroll
            for (int n = 0; n < 4; ++n) {
                int d0 = nBase + wc * 64 + n * 16 + lh * 4;
                int h = d0 >> 6, d = d0 & 63;
                float4 bv = *(const float4*)(&bi[d0]);
                ushort4 o;
                o.x = f2bf(acc[m][n][0] + bv.x * bscl);
                o.y = f2bf(acc[m][n][1] + bv.y * bscl);
                o.z = f2bf(acc[m][n][2] + bv.z * bscl);
                o.w = f2bf(acc[m][n][3] + bv.w * bscl);
                *(ushort4*)(&out[(((size_t)(b * NHEADS + h) * SEQ + s) << 6) + d]) = o;
            }
        }
    } else {
        // V: [bh][d][s'] f16, s' = pi(s); 4 consecutive s -> ushort4.
        #pragma unroll
        for (int m = 0; m < 4; ++m) {
            #pragma unroll
            for (int n = 0; n < 4; ++n) {
                int colg = nBase + wc * 64 + n * 16 + l15;
                float bv = bi[colg];
                int h = colg >> 6, d = colg & 63;
                int rowg0 = mBase + wr * 64 + m * 16 + lh * 4;
                int b = rowg0 >> 11, s = rowg0 & 2047;
                int sp = (s & ~0x3C) | (((s >> 2) & 3) << 4) | (((s >> 4) & 3) << 2);
                ushort4 o;
                o.x = f2h(acc[m][n][0] + bv);
                o.y = f2h(acc[m][n][1] + bv);
                o.z = f2h(acc[m][n][2] + bv);
                o.w = f2h(acc[m][n][3] + bv);
                *(ushort4*)(&out[(((size_t)(b * NHEADS + h) * 64 + d) << 11) + sp]) = o;
            }
        }
    }
}

// ---------------- flash attention (swapped-QK^T, register softmax, exp2 domain) ----------------
// grid: (SEQ/128, NBH, SPLIT?2:1). 8 waves x 16 q-rows (q = lane&15). KV tile = 64, dbuf,
// one barrier per tile. Mask staged to LDS once, folded in as MFMA C-init.
// Ballot-first defer-max; lazy lrun; partial O stored f16.
template<bool SPLIT>
__launch_bounds__(512)
__global__ void attn_kernel(const u16* __restrict__ Qg, const u16* __restrict__ Kg,
                            const u16* __restrict__ Vg,
                            const float* __restrict__ maskL, float* __restrict__ out,
                            u16* __restrict__ OpartH, float* __restrict__ MLpart) {
    __shared__ u16 Ks[2][64 * 64];
    __shared__ u16 Vt[2][64 * 64];
    __shared__ float maskLds[2048];

    const int tid  = threadIdx.x;
    const int lane = tid & 63;
    const int wid  = tid >> 6;
    const int bh = blockIdx.y;
    const int b = bh / NHEADS;
    const int h = bh % NHEADS;
    const int q0 = blockIdx.x * 128 + wid * 16;
    const int l15 = lane & 15, lh = lane >> 4;
    const int z = SPLIT ? blockIdx.z : 0;
    const int NT = SPLIT ? (SEQ / 128) : (SEQ / 64);
    const int tile0 = z * NT;

    // mask slice -> LDS once (NT*64 floats)
    for (int i = tid * 4; i < NT * 64; i += 512 * 4)
        *(float4*)(&maskLds[i]) = *(const float4*)(&maskL[(size_t)b * SEQ + (tile0 << 6) + i]);

    // staging: 512 threads x 16B = full 64x64 u16 tile in one gload round.
    const int srow = tid >> 3;
    const int scol = ((tid & 7) * 8) ^ ((srow & 7) << 3);
    const size_t kSrc = (((size_t)bh * SEQ + srow) << 6) + scol + ((size_t)tile0 << 12);
    const size_t vSrc = (((size_t)bh * 64 + srow) << 11) + scol + (size_t)tile0 * 64;
    const int ldsBase = wid * 512;   // u16 units; lane*8 added by HW

    s16x8 qf[2];
    #pragma unroll
    for (int kk = 0; kk < 2; ++kk)
        qf[kk] = *(const s16x8*)(&Qg[(((size_t)bh * SEQ + q0 + l15) << 6) + kk * 32 + lh * 8]);

    f32x4 oacc[4] = {};           // O^T frags: oacc[nd][j] = O[q=l15][d=nd*16+lh*4+j]
    float mrun = -1e30f, lrun = 0.f;   // lrun is per-lane partial (lazy reduce)

    GLOAD_LDS16(&Kg[kSrc], &Ks[0][ldsBase]);
    GLOAD_LDS16(&Vg[vSrc], &Vt[0][ldsBase]);

    for (int t = 0; t < NT; ++t) {
        const int cur = t & 1;
        __syncthreads();
        if (t + 1 < NT) {
            GLOAD_LDS16(&Kg[kSrc + ((size_t)(t + 1) << 12)], &Ks[cur ^ 1][ldsBase]);
            GLOAD_LDS16(&Vg[vSrc + (size_t)(t + 1) * 64],    &Vt[cur ^ 1][ldsBase]);
        }

        // C-init = mask (broadcast LDS read), then S^T = mfma(K, Q) accumulates on top
        f32x4 sacc[4];
        #pragma unroll
        for (int n = 0; n < 4; ++n) {
            float4 mv = *(const float4*)(&maskLds[t * 64 + n * 16 + lh * 4]);
            sacc[n][0] = mv.x; sacc[n][1] = mv.y; sacc[n][2] = mv.z; sacc[n][3] = mv.w;
        }
        __builtin_amdgcn_s_setprio(1);
        #pragma unroll
        for (int kk = 0; kk < 2; ++kk) {
            #pragma unroll
            for (int n = 0; n < 4; ++n) {
                s16x8 kf = *(const s16x8*)(&Ks[cur][SWZ(n * 16 + l15, kk * 32 + lh * 8)]);
                sacc[n] = __builtin_amdgcn_mfma_f32_16x16x32_bf16(kf, qf[kk], sacc[n], 0, 0, 0);
            }
        }
        __builtin_amdgcn_s_setprio(0);

        // lane-local max; cross-lane reduce only when rescale might be needed
        float tmax = sacc[0][0];
        #pragma unroll
        for (int n = 0; n < 4; ++n)
            #pragma unroll
            for (int j = 0; j < 4; ++j)
                tmax = fmaxf(tmax, sacc[n][j]);

        if (!__all(tmax - mrun <= 11.0f)) {
            float rmax = fmaxf(tmax, __shfl_xor(tmax, 16));
            rmax = fmaxf(rmax, __shfl_xor(rmax, 32));
            float mnew = fmaxf(mrun, rmax);
            float alpha = __builtin_amdgcn_exp2f(mrun - mnew);
            lrun *= alpha;
            #pragma unroll
            for (int nd = 0; nd < 4; ++nd)
                #pragma unroll
                for (int j = 0; j < 4; ++j)
                    oacc[nd][j] *= alpha;
            mrun = mnew;
        }

        f16x4 pf[4];   // B-frag (16x16x16): k = lh*4 + e == S^T D-layout
        #pragma unroll
        for (int n = 0; n < 4; ++n) {
            float p0 = __builtin_amdgcn_exp2f(sacc[n][0] - mrun);
            float p1 = __builtin_amdgcn_exp2f(sacc[n][1] - mrun);
            float p2 = __builtin_amdgcn_exp2f(sacc[n][2] - mrun);
            float p3 = __builtin_amdgcn_exp2f(sacc[n][3] - mrun);
            lrun += (p0 + p1) + (p2 + p3);
            pf[n] = pack4(p0, p1, p2, p3);
        }

        // PV: one 16B read covers frags n=2kk,2kk+1 (pi-permuted V layout)
        __builtin_amdgcn_s_setprio(1);
        #pragma unroll
        for (int kk = 0; kk < 2; ++kk) {
            #pragma unroll
            for (int nd = 0; nd < 4; ++nd) {
                s16x8 v2 = *(const s16x8*)(&Vt[cur][SWZ(nd * 16 + l15, lh * 16 + kk * 8)]);
                union { s16x8 s8; f16x4 h4[2]; } u; u.s8 = v2;
                oacc[nd] = __builtin_amdgcn_mfma_f32_16x16x16f16(u.h4[0], pf[2 * kk],     oacc[nd], 0, 0, 0);
                oacc[nd] = __builtin_amdgcn_mfma_f32_16x16x16f16(u.h4[1], pf[2 * kk + 1], oacc[nd], 0, 0, 0);
            }
        }
        __builtin_amdgcn_s_setprio(0);
    }

    // lazy lrun: reduce across the 4 lh groups sharing each q
    lrun += __shfl_xor(lrun, 16);
    lrun += __shfl_xor(lrun, 32);

    const float inv = 1.0f / lrun;
    const int s = q0 + l15;
    if (!SPLIT) {
        #pragma unroll
        for (int nd = 0; nd < 4; ++nd) {
            float4 o;
            o.x = oacc[nd][0] * inv; o.y = oacc[nd][1] * inv;
            o.z = oacc[nd][2] * inv; o.w = oacc[nd][3] * inv;
            *(float4*)(&out[(size_t)(b * SEQ + s) * (NHEADS * 64) + h * 64 + nd * 16 + lh * 4]) = o;
        }
    } else {
        const size_t rbase = ((size_t)(z * NBH + bh) * SEQ + s);
        #pragma unroll
        for (int nd = 0; nd < 4; ++nd) {
            union { f16x4 h4; ushort4 u4; } o;
            o.h4 = pack4(oacc[nd][0] * inv, oacc[nd][1] * inv,
                         oacc[nd][2] * inv, oacc[nd][3] * inv);
            *(ushort4*)(&OpartH[rbase * 64 + nd * 16 + lh * 4]) = o.u4;
        }
        if (lh == 0)
            *(float2*)(&MLpart[rbase * 2]) = make_float2(mrun, lrun);
    }
}

// ---------------- split-KV combine (f16 partials) ----------------
__global__ void combine_kernel(const u16* __restrict__ OpartH, const float* __restrict__ MLpart,
                               float* __restrict__ out) {
    int gid = blockIdx.x * 256 + threadIdx.x;   // NBH*SEQ*16 = 786432 threads
    int row = gid >> 4, d4 = gid & 15;
    float2 ml0 = ((const float2*)MLpart)[row];
    float2 ml1 = ((const float2*)MLpart)[NBH * SEQ + row];
    float m = fmaxf(ml0.x, ml1.x);
    float w0 = __builtin_amdgcn_exp2f(ml0.x - m) * ml0.y;
    float w1 = __builtin_amdgcn_exp2f(ml1.x - m) * ml1.y;
    float inv = 1.0f / (w0 + w1);
    w0 *= inv; w1 *= inv;
    union { ushort4 u4; f16x4 h4; } a, c;
    a.u4 = *(const ushort4*)(&OpartH[(size_t)row * 64 + d4 * 4]);
    c.u4 = *(const ushort4*)(&OpartH[(size_t)NBH * SEQ * 64 + (size_t)row * 64 + d4 * 4]);
    float4 o;
    o.x = (float)a.h4[0] * w0 + (float)c.h4[0] * w1;
    o.y = (float)a.h4[1] * w0 + (float)c.h4[1] * w1;
    o.z = (float)a.h4[2] * w0 + (float)c.h4[2] * w1;
    o.w = (float)a.h4[3] * w0 + (float)c.h4[3] * w1;
    int bh = row >> 11, s = row & 2047;
    int b = bh / NHEADS, hh = bh % NHEADS;
    *(float4*)(&out[(size_t)(b * SEQ + s) * (NHEADS * 64) + hh * 64 + d4 * 4]) = o;
}

extern "C" void kernel_launch(void* const* d_in, const int* in_sizes, int n_in,
                              void* d_out, int out_size, void* d_ws, size_t ws_size,
                              hipStream_t stream) {
    const float* hidden  = (const float*)d_in[0];
    const float* context = (const float*)d_in[1];
    const float* mask    = (const float*)d_in[2];
    const float* Wq = (const float*)d_in[3];
    const float* bq = (const float*)d_in[4];
    const float* Wk = (const float*)d_in[5];
    const float* bk = (const float*)d_in[6];
    const float* Wv = (const float*)d_in[7];
    const float* bv = (const float*)d_in[8];
    float* out = (float*)d_out;

    char* ws = (char*)d_ws;
    const size_t XSZ = (size_t)4096 * 768 * 2;
    const size_t WSZ = (size_t)768 * 768 * 2;
    u16* X16  = (u16*)(ws);
    u16* C16  = (u16*)(ws + XSZ);
    u16* W16q = (u16*)(ws + 2 * XSZ);
    u16* W16k = (u16*)(ws + 2 * XSZ + WSZ);
    u16* W16v = (u16*)(ws + 2 * XSZ + 2 * WSZ);
    u16* Q16  = (u16*)(ws + 2 * XSZ + 3 * WSZ);
    u16* K16  = (u16*)(ws + 3 * XSZ + 3 * WSZ);
    u16* V16  = (u16*)(ws + 4 * XSZ + 3 * WSZ);    // f16, [bh][d][s'] pi-permuted
    const size_t MASKL_OFF = 5 * XSZ + 3 * WSZ;
    float* maskL = (float*)(ws + MASKL_OFF);
    const size_t OPART_OFF = MASKL_OFF + 2 * SEQ * sizeof(float) + 256;
    u16* OpartH = (u16*)(ws + OPART_OFF);                           // 12.6 MB f16
    const size_t ML_OFF = OPART_OFF + (size_t)2 * NBH * SEQ * 64 * 2;
    float* MLpart = (float*)(ws + ML_OFF);
    const size_t WS_NEED_SPLIT = ML_OFF + (size_t)2 * NBH * SEQ * 2 * 4;

    const float qscl = (float)((1.0 / sqrt(64.0 + 1e-5)) * 1.44269504088896);

    const int n4x = 4096 * 768 / 4;
    const int n4w = 768 * 768 / 4;
    cvt6_kernel<<<dim3((n4x + 255) / 256, 1, 6), 256, 0, stream>>>(
        hidden, context, Wq, Wk, Wv, mask,
        X16, C16, W16q, W16k, W16v, maskL, n4x, n4w, qscl);

    qkv_gemm<<<dim3(4096 / 128, 768 / 128, 3), 256, 0, stream>>>(
        X16, C16, W16q, W16k, W16v, bq, bk, bv, Q16, K16, V16, qscl);

    if (ws_size >= WS_NEED_SPLIT) {
        attn_kernel<true><<<dim3(SEQ / 128, NBH, 2), 512, 0, stream>>>(
            Q16, K16, V16, maskL, out, OpartH, MLpart);
        combine_kernel<<<(NBH * SEQ * 16) / 256, 256, 0, stream>>>(OpartH, MLpart, out);
    } else {
        attn_kernel<false><<<dim3(SEQ / 128, NBH, 1), 512, 0, stream>>>(
            Q16, K16, V16, maskL, out, OpartH, MLpart);
    }
}

// Round 11
// 93.405 us; speedup vs baseline: 2.5574x; 1.0858x over previous
//
#include <hip/hip_runtime.h>
#include <hip/hip_bf16.h>
#include <math.h>

typedef short s16x8 __attribute__((ext_vector_type(8)));
typedef float f32x4 __attribute__((ext_vector_type(4)));
typedef _Float16 f16x4 __attribute__((ext_vector_type(4)));
typedef __fp16 fp16x2 __attribute__((ext_vector_type(2)));
typedef unsigned short u16;

#define NHEADS 12
#define SEQ 2048
#define NBH 24          // B*H
#define KDIM 768
#define LOG2E 1.44269504088896f

// XOR swizzle for u16 tiles with 64-u16 (128 B) rows, 8-u16 (16 B) granularity.
#define SWZ(row, col) (((row) * 64) + ((col) ^ (((row) & 7) << 3)))

// global -> LDS direct, 16B per lane. LDS dest = wave-uniform base + lane*16.
#define GLOAD_LDS16(g, l) __builtin_amdgcn_global_load_lds( \
    (const __attribute__((address_space(1))) unsigned int*)(g), \
    (__attribute__((address_space(3))) unsigned int*)(l), 16, 0, 0)

static __device__ __forceinline__ u16 f2bf(float f) {
    union { float f; unsigned u; } v; v.f = f;
    unsigned r = v.u + 0x7fffu + ((v.u >> 16) & 1u);
    return (u16)(r >> 16);
}
static __device__ __forceinline__ u16 f2h(float f) {
    union { _Float16 h; u16 u; } v; v.h = (_Float16)f;
    return v.u;
}
static __device__ __forceinline__ f16x4 pack4(float a, float b, float c, float d) {
    union { fp16x2 h2[2]; f16x4 h4; } u;
    u.h2[0] = __builtin_amdgcn_cvt_pkrtz(a, b);
    u.h2[1] = __builtin_amdgcn_cvt_pkrtz(c, d);
    return u.h4;
}

// ---------------- f32 -> bf16 convert (z selects tensor; z=2 scales Wq; z=5 mask*log2e f32) ----
__global__ void cvt6_kernel(const float* __restrict__ s0, const float* __restrict__ s1,
                            const float* __restrict__ s2, const float* __restrict__ s3,
                            const float* __restrict__ s4, const float* __restrict__ s5,
                            u16* __restrict__ d0, u16* __restrict__ d1, u16* __restrict__ d2,
                            u16* __restrict__ d3, u16* __restrict__ d4, float* __restrict__ d5,
                            int n4a, int n4w, float qscl) {
    const int z = blockIdx.z;
    int i = blockIdx.x * blockDim.x + threadIdx.x;
    if (z == 5) {
        if (i < (2 * SEQ) / 4) {
            float4 f = ((const float4*)s5)[i];
            f.x *= LOG2E; f.y *= LOG2E; f.z *= LOG2E; f.w *= LOG2E;
            ((float4*)d5)[i] = f;
        }
        return;
    }
    const float* src = (z == 0) ? s0 : (z == 1) ? s1 : (z == 2) ? s2 : (z == 3) ? s3 : s4;
    u16* dst         = (z == 0) ? d0 : (z == 1) ? d1 : (z == 2) ? d2 : (z == 3) ? d3 : d4;
    const int n4     = (z < 2) ? n4a : n4w;
    const float scl  = (z == 2) ? qscl : 1.0f;
    if (i < n4) {
        float4 f = ((const float4*)src)[i];
        ushort4 o;
        o.x = f2bf(f.x * scl); o.y = f2bf(f.y * scl); o.z = f2bf(f.z * scl); o.w = f2bf(f.w * scl);
        ((ushort4*)dst)[i] = o;
    }
}

// ---------------- QKV projection GEMM ----------------
// BK=32, 3-buffer LDS pipeline (48KB), 2-deep prefetch, 1 raw barrier + counted
// vmcnt(4) per K-step (never drains the load pipe until the last iter).
// Tile stored PACKED [64][64]: prow=row>>1, pcol=(row&1)*32+col -> proven SWZ geometry.
// z<2 (Q,K): MFMA operands SWAPPED (A=W, B=X) -> reg j spans d -> ushort4 stores.
// z=2 (V):   normal order; TRANSPOSED+pi-PERMUTED [bh][d][s'] f16 output.
__launch_bounds__(256)
__global__ void qkv_gemm(const u16* __restrict__ X, const u16* __restrict__ C,
                         const u16* __restrict__ W0, const u16* __restrict__ W1, const u16* __restrict__ W2,
                         const float* __restrict__ b0, const float* __restrict__ b1, const float* __restrict__ b2,
                         u16* __restrict__ Qo, u16* __restrict__ Ko, u16* __restrict__ Vo, float qscl) {
    const int z = blockIdx.z;
    const u16* A    = (z == 0) ? X  : C;
    const u16* W    = (z == 0) ? W0 : (z == 1) ? W1 : W2;
    const float* bi = (z == 0) ? b0 : (z == 1) ? b1 : b2;
    u16* out        = (z == 0) ? Qo : (z == 1) ? Ko : Vo;
    const float bscl = (z == 0) ? qscl : 1.0f;

    __shared__ u16 As[3][4096];   // 8KB each: packed 64x64 view of 128x32 tile
    __shared__ u16 Bs[3][4096];

    const int tid  = threadIdx.x;
    const int lane = tid & 63;
    const int wid  = tid >> 6;
    const int wr = wid >> 1, wc = wid & 1;
    const int l15 = lane & 15, lh = lane >> 4;
    const int mBase = blockIdx.x * 128;
    const int nBase = blockIdx.y * 128;

    // staging: 2 chunks/wave/matrix. Content at linear L = swizzled packed tile;
    // invert: prow=L>>6, pcol=(L&63)^((prow&7)<<3), row=(prow<<1)|(pcol>>5), col=pcol&31.
    size_t aSrc[2], bSrc[2]; int ldsOff[2];
    #pragma unroll
    for (int i = 0; i < 2; ++i) {
        int L = i * 2048 + tid * 8;
        int prow = L >> 6;
        int pcol = (L & 63) ^ ((prow & 7) << 3);
        int row = (prow << 1) | (pcol >> 5);
        int col = pcol & 31;
        aSrc[i] = (size_t)(mBase + row) * KDIM + col;
        bSrc[i] = (size_t)(nBase + row) * KDIM + col;
        ldsOff[i] = i * 2048 + wid * 512;   // wave-uniform base; HW adds lane*16B
    }

#define G_STAGE(step, buf) do { \
        const size_t kb_ = (size_t)(step) * 32; \
        GLOAD_LDS16(&A[aSrc[0] + kb_], &As[buf][ldsOff[0]]); \
        GLOAD_LDS16(&A[aSrc[1] + kb_], &As[buf][ldsOff[1]]); \
        GLOAD_LDS16(&W[bSrc[0] + kb_], &Bs[buf][ldsOff[0]]); \
        GLOAD_LDS16(&W[bSrc[1] + kb_], &Bs[buf][ldsOff[1]]); \
    } while (0)

    f32x4 acc[4][4] = {};

    G_STAGE(0, 0);
    G_STAGE(1, 1);

    const int NIT = KDIM / 32;   // 24
    int cur = 0;
    for (int it = 0; it < NIT; ++it) {
        if (it + 1 < NIT) asm volatile("s_waitcnt vmcnt(4)" ::: "memory");
        else              asm volatile("s_waitcnt vmcnt(0)" ::: "memory");
        __builtin_amdgcn_s_barrier();
        __builtin_amdgcn_sched_barrier(0);

        s16x8 xf[4], wf[4];
        #pragma unroll
        for (int m = 0; m < 4; ++m) {
            int row = wr * 64 + m * 16 + l15;
            xf[m] = *(const s16x8*)(&As[cur][SWZ(row >> 1, (row & 1) * 32 + lh * 8)]);
        }
        #pragma unroll
        for (int n = 0; n < 4; ++n) {
            int row = wc * 64 + n * 16 + l15;
            wf[n] = *(const s16x8*)(&Bs[cur][SWZ(row >> 1, (row & 1) * 32 + lh * 8)]);
        }
        if (z < 2) {  // wave-uniform: swapped operands (D: col=s-row, reg=d-col)
            #pragma unroll
            for (int m = 0; m < 4; ++m)
                #pragma unroll
                for (int n = 0; n < 4; ++n)
                    acc[m][n] = __builtin_amdgcn_mfma_f32_16x16x32_bf16(wf[n], xf[m], acc[m][n], 0, 0, 0);
        } else {
            #pragma unroll
            for (int m = 0; m < 4; ++m)
                #pragma unroll
                for (int n = 0; n < 4; ++n)
                    acc[m][n] = __builtin_amdgcn_mfma_f32_16x16x32_bf16(xf[m], wf[n], acc[m][n], 0, 0, 0);
        }

        if (it + 2 < NIT) {
            int nxt = cur + 2; if (nxt >= 3) nxt -= 3;
            G_STAGE(it + 2, nxt);
        }
        ++cur; if (cur == 3) cur = 0;
    }
#undef G_STAGE

    if (z < 2) {
        // D[col=l15 -> s within m-block][reg j -> d within n-block]: ushort4 per (m,n)
        #pragma unroll
        for (int m = 0; m < 4; ++m) {
            int sg = mBase + wr * 64 + m * 16 + l15;
            int b = sg >> 11, s = sg & 2047;
            #pragma unroll
            for (int n = 0; n < 4; ++n) {
                int d0 = nBase + wc * 64 + n * 16 + lh * 4;
                int h = d0 >> 6, d = d0 & 63;
                float4 bv = *(const float4*)(&bi[d0]);
                ushort4 o;
                o.x = f2bf(acc[m][n][0] + bv.x * bscl);
                o.y = f2bf(acc[m][n][1] + bv.y * bscl);
                o.z = f2bf(acc[m][n][2] + bv.z * bscl);
                o.w = f2bf(acc[m][n][3] + bv.w * bscl);
                *(ushort4*)(&out[(((size_t)(b * NHEADS + h) * SEQ + s) << 6) + d]) = o;
            }
        }
    } else {
        // V: [bh][d][s'] f16, s' = pi(s); 4 consecutive s -> ushort4.
        #pragma unroll
        for (int m = 0; m < 4; ++m) {
            #pragma unroll
            for (int n = 0; n < 4; ++n) {
                int colg = nBase + wc * 64 + n * 16 + l15;
                float bv = bi[colg];
                int h = colg >> 6, d = colg & 63;
                int rowg0 = mBase + wr * 64 + m * 16 + lh * 4;
                int b = rowg0 >> 11, s = rowg0 & 2047;
                int sp = (s & ~0x3C) | (((s >> 2) & 3) << 4) | (((s >> 4) & 3) << 2);
                ushort4 o;
                o.x = f2h(acc[m][n][0] + bv);
                o.y = f2h(acc[m][n][1] + bv);
                o.z = f2h(acc[m][n][2] + bv);
                o.w = f2h(acc[m][n][3] + bv);
                *(ushort4*)(&out[(((size_t)(b * NHEADS + h) * 64 + d) << 11) + sp]) = o;
            }
        }
    }
}

// ---------------- flash attention (swapped-QK^T, register softmax, exp2 domain) ----------------
// grid: (SEQ/128, NBH, SPLIT?2:1). 8 waves x 16 q-rows (q = lane&15). KV tile = 64, dbuf,
// one barrier per tile. Mask staged to LDS once, folded in as MFMA C-init.
// Ballot-first defer-max; lazy lrun; partial O stored f16.
template<bool SPLIT>
__launch_bounds__(512)
__global__ void attn_kernel(const u16* __restrict__ Qg, const u16* __restrict__ Kg,
                            const u16* __restrict__ Vg,
                            const float* __restrict__ maskL, float* __restrict__ out,
                            u16* __restrict__ OpartH, float* __restrict__ MLpart) {
    __shared__ u16 Ks[2][64 * 64];
    __shared__ u16 Vt[2][64 * 64];
    __shared__ float maskLds[2048];

    const int tid  = threadIdx.x;
    const int lane = tid & 63;
    const int wid  = tid >> 6;
    const int bh = blockIdx.y;
    const int b = bh / NHEADS;
    const int h = bh % NHEADS;
    const int q0 = blockIdx.x * 128 + wid * 16;
    const int l15 = lane & 15, lh = lane >> 4;
    const int z = SPLIT ? blockIdx.z : 0;
    const int NT = SPLIT ? (SEQ / 128) : (SEQ / 64);
    const int tile0 = z * NT;

    // mask slice -> LDS once (NT*64 floats)
    for (int i = tid * 4; i < NT * 64; i += 512 * 4)
        *(float4*)(&maskLds[i]) = *(const float4*)(&maskL[(size_t)b * SEQ + (tile0 << 6) + i]);

    // staging: 512 threads x 16B = full 64x64 u16 tile in one gload round.
    const int srow = tid >> 3;
    const int scol = ((tid & 7) * 8) ^ ((srow & 7) << 3);
    const size_t kSrc = (((size_t)bh * SEQ + srow) << 6) + scol + ((size_t)tile0 << 12);
    const size_t vSrc = (((size_t)bh * 64 + srow) << 11) + scol + (size_t)tile0 * 64;
    const int ldsBase = wid * 512;   // u16 units; lane*8 added by HW

    s16x8 qf[2];
    #pragma unroll
    for (int kk = 0; kk < 2; ++kk)
        qf[kk] = *(const s16x8*)(&Qg[(((size_t)bh * SEQ + q0 + l15) << 6) + kk * 32 + lh * 8]);

    f32x4 oacc[4] = {};           // O^T frags: oacc[nd][j] = O[q=l15][d=nd*16+lh*4+j]
    float mrun = -1e30f, lrun = 0.f;   // lrun is per-lane partial (lazy reduce)

    GLOAD_LDS16(&Kg[kSrc], &Ks[0][ldsBase]);
    GLOAD_LDS16(&Vg[vSrc], &Vt[0][ldsBase]);

    for (int t = 0; t < NT; ++t) {
        const int cur = t & 1;
        __syncthreads();
        if (t + 1 < NT) {
            GLOAD_LDS16(&Kg[kSrc + ((size_t)(t + 1) << 12)], &Ks[cur ^ 1][ldsBase]);
            GLOAD_LDS16(&Vg[vSrc + (size_t)(t + 1) * 64],    &Vt[cur ^ 1][ldsBase]);
        }

        // C-init = mask (broadcast LDS read), then S^T = mfma(K, Q) accumulates on top
        f32x4 sacc[4];
        #pragma unroll
        for (int n = 0; n < 4; ++n) {
            float4 mv = *(const float4*)(&maskLds[t * 64 + n * 16 + lh * 4]);
            sacc[n][0] = mv.x; sacc[n][1] = mv.y; sacc[n][2] = mv.z; sacc[n][3] = mv.w;
        }
        __builtin_amdgcn_s_setprio(1);
        #pragma unroll
        for (int kk = 0; kk < 2; ++kk) {
            #pragma unroll
            for (int n = 0; n < 4; ++n) {
                s16x8 kf = *(const s16x8*)(&Ks[cur][SWZ(n * 16 + l15, kk * 32 + lh * 8)]);
                sacc[n] = __builtin_amdgcn_mfma_f32_16x16x32_bf16(kf, qf[kk], sacc[n], 0, 0, 0);
            }
        }
        __builtin_amdgcn_s_setprio(0);

        // lane-local max; cross-lane reduce only when rescale might be needed
        float tmax = sacc[0][0];
        #pragma unroll
        for (int n = 0; n < 4; ++n)
            #pragma unroll
            for (int j = 0; j < 4; ++j)
                tmax = fmaxf(tmax, sacc[n][j]);

        if (!__all(tmax - mrun <= 11.0f)) {
            float rmax = fmaxf(tmax, __shfl_xor(tmax, 16));
            rmax = fmaxf(rmax, __shfl_xor(rmax, 32));
            float mnew = fmaxf(mrun, rmax);
            float alpha = __builtin_amdgcn_exp2f(mrun - mnew);
            lrun *= alpha;
            #pragma unroll
            for (int nd = 0; nd < 4; ++nd)
                #pragma unroll
                for (int j = 0; j < 4; ++j)
                    oacc[nd][j] *= alpha;
            mrun = mnew;
        }

        f16x4 pf[4];   // B-frag (16x16x16): k = lh*4 + e == S^T D-layout
        #pragma unroll
        for (int n = 0; n < 4; ++n) {
            float p0 = __builtin_amdgcn_exp2f(sacc[n][0] - mrun);
            float p1 = __builtin_amdgcn_exp2f(sacc[n][1] - mrun);
            float p2 = __builtin_amdgcn_exp2f(sacc[n][2] - mrun);
            float p3 = __builtin_amdgcn_exp2f(sacc[n][3] - mrun);
            lrun += (p0 + p1) + (p2 + p3);
            pf[n] = pack4(p0, p1, p2, p3);
        }

        // PV: one 16B read covers frags n=2kk,2kk+1 (pi-permuted V layout)
        __builtin_amdgcn_s_setprio(1);
        #pragma unroll
        for (int kk = 0; kk < 2; ++kk) {
            #pragma unroll
            for (int nd = 0; nd < 4; ++nd) {
                s16x8 v2 = *(const s16x8*)(&Vt[cur][SWZ(nd * 16 + l15, lh * 16 + kk * 8)]);
                union { s16x8 s8; f16x4 h4[2]; } u; u.s8 = v2;
                oacc[nd] = __builtin_amdgcn_mfma_f32_16x16x16f16(u.h4[0], pf[2 * kk],     oacc[nd], 0, 0, 0);
                oacc[nd] = __builtin_amdgcn_mfma_f32_16x16x16f16(u.h4[1], pf[2 * kk + 1], oacc[nd], 0, 0, 0);
            }
        }
        __builtin_amdgcn_s_setprio(0);
    }

    // lazy lrun: reduce across the 4 lh groups sharing each q
    lrun += __shfl_xor(lrun, 16);
    lrun += __shfl_xor(lrun, 32);

    const float inv = 1.0f / lrun;
    const int s = q0 + l15;
    if (!SPLIT) {
        #pragma unroll
        for (int nd = 0; nd < 4; ++nd) {
            float4 o;
            o.x = oacc[nd][0] * inv; o.y = oacc[nd][1] * inv;
            o.z = oacc[nd][2] * inv; o.w = oacc[nd][3] * inv;
            *(float4*)(&out[(size_t)(b * SEQ + s) * (NHEADS * 64) + h * 64 + nd * 16 + lh * 4]) = o;
        }
    } else {
        const size_t rbase = ((size_t)(z * NBH + bh) * SEQ + s);
        #pragma unroll
        for (int nd = 0; nd < 4; ++nd) {
            union { f16x4 h4; ushort4 u4; } o;
            o.h4 = pack4(oacc[nd][0] * inv, oacc[nd][1] * inv,
                         oacc[nd][2] * inv, oacc[nd][3] * inv);
            *(ushort4*)(&OpartH[rbase * 64 + nd * 16 + lh * 4]) = o.u4;
        }
        if (lh == 0)
            *(float2*)(&MLpart[rbase * 2]) = make_float2(mrun, lrun);
    }
}

// ---------------- split-KV combine (f16 partials) ----------------
__global__ void combine_kernel(const u16* __restrict__ OpartH, const float* __restrict__ MLpart,
                               float* __restrict__ out) {
    int gid = blockIdx.x * 256 + threadIdx.x;   // NBH*SEQ*16 = 786432 threads
    int row = gid >> 4, d4 = gid & 15;
    float2 ml0 = ((const float2*)MLpart)[row];
    float2 ml1 = ((const float2*)MLpart)[NBH * SEQ + row];
    float m = fmaxf(ml0.x, ml1.x);
    float w0 = __builtin_amdgcn_exp2f(ml0.x - m) * ml0.y;
    float w1 = __builtin_amdgcn_exp2f(ml1.x - m) * ml1.y;
    float inv = 1.0f / (w0 + w1);
    w0 *= inv; w1 *= inv;
    union { ushort4 u4; f16x4 h4; } a, c;
    a.u4 = *(const ushort4*)(&OpartH[(size_t)row * 64 + d4 * 4]);
    c.u4 = *(const ushort4*)(&OpartH[(size_t)NBH * SEQ * 64 + (size_t)row * 64 + d4 * 4]);
    float4 o;
    o.x = (float)a.h4[0] * w0 + (float)c.h4[0] * w1;
    o.y = (float)a.h4[1] * w0 + (float)c.h4[1] * w1;
    o.z = (float)a.h4[2] * w0 + (float)c.h4[2] * w1;
    o.w = (float)a.h4[3] * w0 + (float)c.h4[3] * w1;
    int bh = row >> 11, s = row & 2047;
    int b = bh / NHEADS, hh = bh % NHEADS;
    *(float4*)(&out[(size_t)(b * SEQ + s) * (NHEADS * 64) + hh * 64 + d4 * 4]) = o;
}

extern "C" void kernel_launch(void* const* d_in, const int* in_sizes, int n_in,
                              void* d_out, int out_size, void* d_ws, size_t ws_size,
                              hipStream_t stream) {
    const float* hidden  = (const float*)d_in[0];
    const float* context = (const float*)d_in[1];
    const float* mask    = (const float*)d_in[2];
    const float* Wq = (const float*)d_in[3];
    const float* bq = (const float*)d_in[4];
    const float* Wk = (const float*)d_in[5];
    const float* bk = (const float*)d_in[6];
    const float* Wv = (const float*)d_in[7];
    const float* bv = (const float*)d_in[8];
    float* out = (float*)d_out;

    char* ws = (char*)d_ws;
    const size_t XSZ = (size_t)4096 * 768 * 2;
    const size_t WSZ = (size_t)768 * 768 * 2;
    u16* X16  = (u16*)(ws);
    u16* C16  = (u16*)(ws + XSZ);
    u16* W16q = (u16*)(ws + 2 * XSZ);
    u16* W16k = (u16*)(ws + 2 * XSZ + WSZ);
    u16* W16v = (u16*)(ws + 2 * XSZ + 2 * WSZ);
    u16* Q16  = (u16*)(ws + 2 * XSZ + 3 * WSZ);
    u16* K16  = (u16*)(ws + 3 * XSZ + 3 * WSZ);
    u16* V16  = (u16*)(ws + 4 * XSZ + 3 * WSZ);    // f16, [bh][d][s'] pi-permuted
    const size_t MASKL_OFF = 5 * XSZ + 3 * WSZ;
    float* maskL = (float*)(ws + MASKL_OFF);
    const size_t OPART_OFF = MASKL_OFF + 2 * SEQ * sizeof(float) + 256;
    u16* OpartH = (u16*)(ws + OPART_OFF);                           // 12.6 MB f16
    const size_t ML_OFF = OPART_OFF + (size_t)2 * NBH * SEQ * 64 * 2;
    float* MLpart = (float*)(ws + ML_OFF);
    const size_t WS_NEED_SPLIT = ML_OFF + (size_t)2 * NBH * SEQ * 2 * 4;

    const float qscl = (float)((1.0 / sqrt(64.0 + 1e-5)) * 1.44269504088896);

    const int n4x = 4096 * 768 / 4;
    const int n4w = 768 * 768 / 4;
    cvt6_kernel<<<dim3((n4x + 255) / 256, 1, 6), 256, 0, stream>>>(
        hidden, context, Wq, Wk, Wv, mask,
        X16, C16, W16q, W16k, W16v, maskL, n4x, n4w, qscl);

    qkv_gemm<<<dim3(4096 / 128, 768 / 128, 3), 256, 0, stream>>>(
        X16, C16, W16q, W16k, W16v, bq, bk, bv, Q16, K16, V16, qscl);

    if (ws_size >= WS_NEED_SPLIT) {
        attn_kernel<true><<<dim3(SEQ / 128, NBH, 2), 512, 0, stream>>>(
            Q16, K16, V16, maskL, out, OpartH, MLpart);
        combine_kernel<<<(NBH * SEQ * 16) / 256, 256, 0, stream>>>(OpartH, MLpart, out);
    } else {
        attn_kernel<false><<<dim3(SEQ / 128, NBH, 1), 512, 0, stream>>>(
            Q16, K16, V16, maskL, out, OpartH, MLpart);
    }
}